// Round 12
// baseline (38.793 us; speedup 1.0000x reference)
//
#include <hip/hip_runtime.h>

#define BB 8
#define CC 20
#define HH 384
#define WW 384
#define NPIX (BB*HH*WW)
#define BIGF 1.0e6f
#define PADSQ 3.0e12f
#define INFF 1.0e30f
#define HALO 8
#define SROW (WW + 2*HALO)     // 400 pixel slots (x in [-8, 391])

// ws layout: wq[2*NPIX] (interleaved d1^2 mask0/mask1), bsum[BB*HH].

// Kernel 1: vertical EDT for both masks, wave-parallel prefix/suffix min-scan.
// One wave per (b,x) column; block = 4 adjacent columns. NEW: tgt is read as
// one int4 per row (covers all 4 columns) into packed 2-bit codes staged in
// LDS -> 4x fewer scattered read transactions; scan math and the output
// stores are unchanged from the proven R11 version.
__global__ __launch_bounds__(256) void edt_vertical(const int* __restrict__ tgt,
                                                    float* __restrict__ wq) {
    __shared__ unsigned int codes[HH];   // one u32 per row: 4 columns x 1 byte

    int tid = threadIdx.x;
    int lane = tid & 63;
    int w = tid >> 6;                    // wave id = column offset within block
    int col = blockIdx.x * 4 + w;        // global column 0..3071
    int b = (blockIdx.x * 4) / WW;       // all 4 columns in same image
    int xb = (blockIdx.x * 4) % WW;      // block's first x (multiple of 4)

    // Phase 1: cooperative coalesced-ish load: one int4 per row -> packed code
    const int4* tp4 = (const int4*)(tgt + (size_t)b * HH * WW + xb);
    #pragma unroll
    for (int i = 0; i < 2; ++i) {
        int y = w * 96 + i * 64 + lane;  // w*96 + [0..95]
        if (i == 0 || lane < 32) {
            int4 v = tp4[(size_t)y * (WW / 4)];
            unsigned c0 = (v.x == 0 ? 1u : 0u) | (v.x == 1 ? 2u : 0u);
            unsigned c1 = (v.y == 0 ? 1u : 0u) | (v.y == 1 ? 2u : 0u);
            unsigned c2 = (v.z == 0 ? 1u : 0u) | (v.z == 1 ? 2u : 0u);
            unsigned c3 = (v.w == 0 ? 1u : 0u) | (v.w == 1 ? 2u : 0u);
            codes[y] = c0 | (c1 << 8) | (c2 << 16) | (c3 << 24);
        }
    }
    __syncthreads();

    int y0 = lane * 6;
    int shift = 8 * w;
    unsigned cv[6];
    #pragma unroll
    for (int k = 0; k < 6; ++k) cv[k] = (codes[y0 + k] >> shift) & 3u;

    float* op = wq + 2 * ((size_t)b * HH * WW + (col % WW));
    float d0sq[6];

    #pragma unroll
    for (int m = 0; m < 2; ++m) {
        float p[6];
        float run = INFF;
        #pragma unroll
        for (int k = 0; k < 6; ++k) {
            float c = ((cv[k] >> m) & 1u) ? 0.0f : BIGF;
            run = fminf(run, c - (float)(y0 + k));
            p[k] = run;
        }
        float s = run;
        #pragma unroll
        for (int off = 1; off < 64; off <<= 1) {
            float o = __shfl_up(s, off);
            if (lane >= off) s = fminf(s, o);
        }
        float carry = __shfl_up(s, 1);
        if (lane == 0) carry = INFF;

        float q[6];
        run = INFF;
        #pragma unroll
        for (int k = 5; k >= 0; --k) {
            float c = ((cv[k] >> m) & 1u) ? 0.0f : BIGF;
            run = fminf(run, c + (float)(y0 + k));
            q[k] = run;
        }
        float sb = run;
        #pragma unroll
        for (int off = 1; off < 64; off <<= 1) {
            float o = __shfl_down(sb, off);
            if (lane < 64 - off) sb = fminf(sb, o);
        }
        float carryb = __shfl_down(sb, 1);
        if (lane == 63) carryb = INFF;

        #pragma unroll
        for (int k = 0; k < 6; ++k) {
            float y = (float)(y0 + k);
            float fwd = y + fminf(carry, p[k]);
            float bwd = fminf(carryb, q[k]) - y;
            float d = fminf(fwd, bwd);
            if (m == 0) {
                d0sq[k] = d * d;
            } else {
                float2 st = make_float2(d0sq[k], d * d);
                *(float2*)(op + (size_t)2 * (y0 + k) * WW) = st;
            }
        }
    }
}

// Kernel 2: R2-structure fused row kernel. One row per block, one pixel per
// thread. Stage interleaved wq row to LDS -> barrier (drains only 3 small
// loads) -> windowed min-plus (+-8, float2 = both masks per ds_read_b64) ->
// TWO-PASS CE with pv[20] held in registers: liveness across the max-pass
// forces the compiler to keep all 20 global loads in flight (proven in R2;
// every 1-pass variant collapsed to serial loads). bsum write, no atomics.
// DO NOT TOUCH THIS BODY (R3-R8, R10: 5/5 perturbations collapsed the MLP).
__global__ __launch_bounds__(384) void loss_rows(const float* __restrict__ pred,
                                                 const int* __restrict__ tgt,
                                                 const float* __restrict__ wq,
                                                 float* __restrict__ bsum) {
    __shared__ float sh[2 * SROW];   // interleaved (m0,m1) pairs, 800 floats
    __shared__ float wred[6];

    int t = threadIdx.x;             // pixel x, 0..383
    int row = blockIdx.x;            // b*HH + y
    int b = row / HH;
    int base = row * WW;             // global pixel index of row start

    // stage wq row (768 valid floats) into 800 LDS slots; slot s <-> wq idx s-16
    const float* wrow = wq + 2 * (size_t)base;
    {
        int f0 = t, f1 = t + 384, f2 = t + 768;
        sh[f0] = (f0 >= 2 * HALO) ? wrow[f0 - 2 * HALO] : PADSQ;
        sh[f1] = wrow[f1 - 2 * HALO];                       // idx 368..751 valid
        if (f2 < 2 * SROW)                                  // t < 32
            sh[f2] = (f2 - 2 * HALO < 2 * WW) ? wrow[f2 - 2 * HALO] : PADSQ;
    }
    __syncthreads();

    // issue all 20 pred loads (held across max-pass below -> 20-deep MLP)
    // in-image offset = (row % HH)*WW + t = base - b*HH*WW + t
    const float* pb = pred + (size_t)b * CC * HH * WW
                    + ((size_t)base - (size_t)b * HH * WW) + t;
    float pv[CC];
    #pragma unroll
    for (int c = 0; c < CC; ++c) pv[c] = pb[(size_t)c * HH * WW];
    int tv = tgt[base + t];

    // windowed min-plus from LDS (overlaps the global loads' latency)
    float m0 = PADSQ, m1 = PADSQ;
    const float2* shp = (const float2*)sh;
    #pragma unroll
    for (int j = 0; j <= 2 * HALO; ++j) {     // window offset j-HALO
        float2 v = shp[t + j];
        float dsq = (float)((j - HALO) * (j - HALO));
        m0 = fminf(m0, v.x + dsq);
        m1 = fminf(m1, v.y + dsq);
    }
    float dist = sqrtf(m0) + sqrtf(m1);
    float wgt = 1.0f + 5.0f * __expf(dist * (-1.0f / 3.0f));

    // two-pass CE (pass 1: max, keeps pv[] live; pass 2: sum of exp)
    float mx = -INFF;
    #pragma unroll
    for (int c = 0; c < CC; ++c) mx = fmaxf(mx, pv[c]);
    float S = 0.0f, pt = 0.0f;
    #pragma unroll
    for (int c = 0; c < CC; ++c) {
        S += __expf(pv[c] - mx);
        if (c == tv) pt = pv[c];
    }
    float ce = mx + __logf(S) - pt;
    float val = ce * wgt;

    // deterministic reduction: wave shfl -> LDS -> bsum[row]
    #pragma unroll
    for (int off = 32; off; off >>= 1) val += __shfl_down(val, off);
    int wid = t >> 6, lane = t & 63;
    if (lane == 0) wred[wid] = val;
    __syncthreads();
    if (t == 0) {
        float s = 0.0f;
        #pragma unroll
        for (int i = 0; i < 6; ++i) s += wred[i];
        bsum[row] = s;
    }
}

// Kernel 3: deterministic final reduction of 3072 block sums -> mean.
__global__ __launch_bounds__(1024) void finalize(const float* __restrict__ bsum,
                                                 float* __restrict__ out) {
    __shared__ float red[16];
    int tid = threadIdx.x;
    float v = 0.0f;
    #pragma unroll
    for (int i = 0; i < 3; ++i) v += bsum[tid + i * 1024];
    #pragma unroll
    for (int off = 32; off; off >>= 1) v += __shfl_down(v, off);
    int wid = tid >> 6, lane = tid & 63;
    if (lane == 0) red[wid] = v;
    __syncthreads();
    if (tid == 0) {
        float s = 0.0f;
        #pragma unroll
        for (int i = 0; i < 16; ++i) s += red[i];
        out[0] = s * (1.0f / (float)NPIX);
    }
}

extern "C" void kernel_launch(void* const* d_in, const int* in_sizes, int n_in,
                              void* d_out, int out_size, void* d_ws, size_t ws_size,
                              hipStream_t stream) {
    const float* pred = (const float*)d_in[0];
    const int* tgt = (const int*)d_in[1];
    float* out = (float*)d_out;

    float* wq = (float*)d_ws;
    float* bsum = wq + (size_t)2 * NPIX;   // BB*HH = 3072 floats

    edt_vertical<<<(BB * WW) / 4, 256, 0, stream>>>(tgt, wq);
    loss_rows<<<BB * HH, 384, 0, stream>>>(pred, tgt, wq, bsum);
    finalize<<<1, 1024, 0, stream>>>(bsum, out);
}

// Round 13
// 38.504 us; speedup vs baseline: 1.0075x; 1.0075x over previous
//
#include <hip/hip_runtime.h>

#define BB 8
#define CC 20
#define HH 384
#define WW 384
#define NPIX (BB*HH*WW)
#define BIGF 1.0e6f
#define PADSQ 3.0e12f
#define INFF 1.0e30f
#define HALO 8
#define SROW (WW + 2*HALO)     // 400 pixel slots (x in [-8, 391])

// ws layout: wq[2*NPIX] (interleaved d1^2 mask0/mask1), bsum[BB*HH].

// Kernel 1: vertical EDT for both masks, wave-parallel prefix/suffix min-scan.
// One wave per (b,x) column; block = 4 adjacent columns; tgt read as one int4
// per row into packed 2-bit codes staged in LDS. (R12 version, byte-identical.)
__global__ __launch_bounds__(256) void edt_vertical(const int* __restrict__ tgt,
                                                    float* __restrict__ wq) {
    __shared__ unsigned int codes[HH];   // one u32 per row: 4 columns x 1 byte

    int tid = threadIdx.x;
    int lane = tid & 63;
    int w = tid >> 6;                    // wave id = column offset within block
    int col = blockIdx.x * 4 + w;        // global column 0..3071
    int b = (blockIdx.x * 4) / WW;       // all 4 columns in same image
    int xb = (blockIdx.x * 4) % WW;      // block's first x (multiple of 4)

    const int4* tp4 = (const int4*)(tgt + (size_t)b * HH * WW + xb);
    #pragma unroll
    for (int i = 0; i < 2; ++i) {
        int y = w * 96 + i * 64 + lane;  // w*96 + [0..95]
        if (i == 0 || lane < 32) {
            int4 v = tp4[(size_t)y * (WW / 4)];
            unsigned c0 = (v.x == 0 ? 1u : 0u) | (v.x == 1 ? 2u : 0u);
            unsigned c1 = (v.y == 0 ? 1u : 0u) | (v.y == 1 ? 2u : 0u);
            unsigned c2 = (v.z == 0 ? 1u : 0u) | (v.z == 1 ? 2u : 0u);
            unsigned c3 = (v.w == 0 ? 1u : 0u) | (v.w == 1 ? 2u : 0u);
            codes[y] = c0 | (c1 << 8) | (c2 << 16) | (c3 << 24);
        }
    }
    __syncthreads();

    int y0 = lane * 6;
    int shift = 8 * w;
    unsigned cv[6];
    #pragma unroll
    for (int k = 0; k < 6; ++k) cv[k] = (codes[y0 + k] >> shift) & 3u;

    float* op = wq + 2 * ((size_t)b * HH * WW + (col % WW));
    float d0sq[6];

    #pragma unroll
    for (int m = 0; m < 2; ++m) {
        float p[6];
        float run = INFF;
        #pragma unroll
        for (int k = 0; k < 6; ++k) {
            float c = ((cv[k] >> m) & 1u) ? 0.0f : BIGF;
            run = fminf(run, c - (float)(y0 + k));
            p[k] = run;
        }
        float s = run;
        #pragma unroll
        for (int off = 1; off < 64; off <<= 1) {
            float o = __shfl_up(s, off);
            if (lane >= off) s = fminf(s, o);
        }
        float carry = __shfl_up(s, 1);
        if (lane == 0) carry = INFF;

        float q[6];
        run = INFF;
        #pragma unroll
        for (int k = 5; k >= 0; --k) {
            float c = ((cv[k] >> m) & 1u) ? 0.0f : BIGF;
            run = fminf(run, c + (float)(y0 + k));
            q[k] = run;
        }
        float sb = run;
        #pragma unroll
        for (int off = 1; off < 64; off <<= 1) {
            float o = __shfl_down(sb, off);
            if (lane < 64 - off) sb = fminf(sb, o);
        }
        float carryb = __shfl_down(sb, 1);
        if (lane == 63) carryb = INFF;

        #pragma unroll
        for (int k = 0; k < 6; ++k) {
            float y = (float)(y0 + k);
            float fwd = y + fminf(carry, p[k]);
            float bwd = fminf(carryb, q[k]) - y;
            float d = fminf(fwd, bwd);
            if (m == 0) {
                d0sq[k] = d * d;
            } else {
                float2 st = make_float2(d0sq[k], d * d);
                *(float2*)(op + (size_t)2 * (y0 + k) * WW) = st;
            }
        }
    }
}

// Kernel 2: 2-pixels-per-thread float2 variant of the proven R11 body.
// Same textual structure (stage -> barrier -> ALL pred loads held across a
// two-pass CE -> window -> reduce); float2 pv[20] = 40 live VGPRs (fits,
// unlike R3's float4=80 which remat'd). Halves per-wave issue count at equal
// byte traffic: this is the issue-bound vs L3-BW-bound discriminator.
__global__ __launch_bounds__(192) void loss_rows(const float* __restrict__ pred,
                                                 const int* __restrict__ tgt,
                                                 const float* __restrict__ wq,
                                                 float* __restrict__ bsum) {
    __shared__ float sh[2 * SROW];   // interleaved (m0,m1) pairs, 800 floats
    __shared__ float wred[3];

    int t = threadIdx.x;             // 0..191, owns pixels {2t, 2t+1}
    int row = blockIdx.x;            // b*HH + y
    int b = row / HH;
    int base = row * WW;             // global pixel index of row start

    // stage wq row (768 valid floats) into 800 LDS slots; slot s <-> wq idx s-16
    const float* wrow = wq + 2 * (size_t)base;
    {
        int f0 = t, f1 = t + 192, f2 = t + 384, f3 = t + 576, f4 = t + 768;
        sh[f0] = (f0 >= 2 * HALO) ? wrow[f0 - 2 * HALO] : PADSQ;
        sh[f1] = wrow[f1 - 2 * HALO];                       // idx 176..367 valid
        sh[f2] = wrow[f2 - 2 * HALO];                       // idx 368..559 valid
        sh[f3] = wrow[f3 - 2 * HALO];                       // idx 560..751 valid
        if (f4 < 2 * SROW)                                  // t < 32
            sh[f4] = (f4 - 2 * HALO < 2 * WW) ? wrow[f4 - 2 * HALO] : PADSQ;
    }
    __syncthreads();

    // issue all 20 float2 pred loads (held across max-pass below -> 20-deep MLP)
    int xg = 2 * t;
    const float* pb = pred + (size_t)b * CC * HH * WW
                    + ((size_t)base - (size_t)b * HH * WW) + xg;
    float2 pv[CC];
    #pragma unroll
    for (int c = 0; c < CC; ++c) pv[c] = *(const float2*)(pb + (size_t)c * HH * WW);
    const int2 tv = *(const int2*)(tgt + base + xg);

    // windowed min-plus from LDS: pairs 2t..2t+17 serve both pixels
    float m0a = PADSQ, m1a = PADSQ;   // pixel 2t
    float m0b = PADSQ, m1b = PADSQ;   // pixel 2t+1
    const float2* shp = (const float2*)sh;
    #pragma unroll
    for (int j = 0; j <= 17; ++j) {
        float2 v = shp[xg + j];
        if (j <= 16) {                 // offset (j-8) for pixel 2t
            float dsq = (float)((j - 8) * (j - 8));
            m0a = fminf(m0a, v.x + dsq);
            m1a = fminf(m1a, v.y + dsq);
        }
        if (j >= 1) {                  // offset (j-9) for pixel 2t+1
            float dsq = (float)((j - 9) * (j - 9));
            m0b = fminf(m0b, v.x + dsq);
            m1b = fminf(m1b, v.y + dsq);
        }
    }
    float dista = sqrtf(m0a) + sqrtf(m1a);
    float distb = sqrtf(m0b) + sqrtf(m1b);
    float wa = 1.0f + 5.0f * __expf(dista * (-1.0f / 3.0f));
    float wb = 1.0f + 5.0f * __expf(distb * (-1.0f / 3.0f));

    // two-pass CE (pass 1: max, keeps pv[] live; pass 2: sum of exp)
    float mxx = -INFF, mxy = -INFF;
    #pragma unroll
    for (int c = 0; c < CC; ++c) {
        mxx = fmaxf(mxx, pv[c].x);
        mxy = fmaxf(mxy, pv[c].y);
    }
    float Sx = 0.0f, Sy = 0.0f, ptx = 0.0f, pty = 0.0f;
    #pragma unroll
    for (int c = 0; c < CC; ++c) {
        Sx += __expf(pv[c].x - mxx);
        Sy += __expf(pv[c].y - mxy);
        if (c == tv.x) ptx = pv[c].x;
        if (c == tv.y) pty = pv[c].y;
    }
    float cea = mxx + __logf(Sx) - ptx;
    float ceb = mxy + __logf(Sy) - pty;
    float val = cea * wa + ceb * wb;

    // deterministic reduction: wave shfl -> LDS -> bsum[row]
    #pragma unroll
    for (int off = 32; off; off >>= 1) val += __shfl_down(val, off);
    int wid = t >> 6, lane = t & 63;
    if (lane == 0) wred[wid] = val;
    __syncthreads();
    if (t == 0) {
        float s = wred[0] + wred[1] + wred[2];
        bsum[row] = s;
    }
}

// Kernel 3: deterministic final reduction of 3072 block sums -> mean.
__global__ __launch_bounds__(1024) void finalize(const float* __restrict__ bsum,
                                                 float* __restrict__ out) {
    __shared__ float red[16];
    int tid = threadIdx.x;
    float v = 0.0f;
    #pragma unroll
    for (int i = 0; i < 3; ++i) v += bsum[tid + i * 1024];
    #pragma unroll
    for (int off = 32; off; off >>= 1) v += __shfl_down(v, off);
    int wid = tid >> 6, lane = tid & 63;
    if (lane == 0) red[wid] = v;
    __syncthreads();
    if (tid == 0) {
        float s = 0.0f;
        #pragma unroll
        for (int i = 0; i < 16; ++i) s += red[i];
        out[0] = s * (1.0f / (float)NPIX);
    }
}

extern "C" void kernel_launch(void* const* d_in, const int* in_sizes, int n_in,
                              void* d_out, int out_size, void* d_ws, size_t ws_size,
                              hipStream_t stream) {
    const float* pred = (const float*)d_in[0];
    const int* tgt = (const int*)d_in[1];
    float* out = (float*)d_out;

    float* wq = (float*)d_ws;
    float* bsum = wq + (size_t)2 * NPIX;   // BB*HH = 3072 floats

    edt_vertical<<<(BB * WW) / 4, 256, 0, stream>>>(tgt, wq);
    loss_rows<<<BB * HH, 192, 0, stream>>>(pred, tgt, wq, bsum);
    finalize<<<1, 1024, 0, stream>>>(bsum, out);
}